// Round 5
// baseline (134.129 us; speedup 1.0000x reference)
//
#include <hip/hip_runtime.h>
#include <math.h>

// Soft silhouette renderer — R23 = R20 base + ACTIVE-EDGE specialization
// of the j-loop (transcendental-issue-bound fix) + exp2-domain coeffs.
// verts: (4, 778, 3) f32   faces: (1538, 3) i32   out: (4, 320, 320) f32
//
// Verified-exact math core (R4, absmax 0.0):
//   area2 = fma(dx1, dy2, -round(dy1*dx2)) — matches the reference
//   evaluator's contraction; degenerate faces (sgn=0 -> 1/8 veil, i1==i2
//   sliver -> sigma=1/2 ridge) fall out of the generic edge code.
//   (Scaling s by log2e preserves sign/zero structure — area2 untouched.)
//
// R22 post-mortem: bbox two-stage regressed (85.9 vs R20 81.7): scattered
// candidate gather (16B/lane from distinct lines) + 7-pass ballot chain
// cost more than the coalesced sweep it replaced. Staging is ~8us of the
// ~40us silhouette; the j-loop (~32us) is the real target and is
// TRANSCENDENTAL-ISSUE-BOUND: per face-visit ~14 full-rate VALU + 4
// quarter-rate trans (3 v_exp + rcp) = ~60 issue-cy; 1.4M face-visits /
// 1024 SIMDs ~= 34us. Matches measurement.
//
// R23 attacks the trans count:
//  * ACTIVE-EDGE MASK: band half-width 12sigma ~ 19px, triangles are
//    ~80-160px => for most band faces only ONE edge is within 13 nats of
//    the whole 8px tile; the other sigmoids are 1 within 2.3e-6. Staging
//    already has tile-wide per-edge bounds (c_i +- r_i): store the active
//    edges PERMUTED FIRST (sE0=first active, sE1=second, sE2=third) with
//    the count in sE0.w. j-loop branches on the wave-uniform count
//    (readfirstlane -> scalar branch):
//      cnt=1: f = rcp(1 + 2^x)            (2 fma + 2 trans, ~26cy vs 60)
//      cnt=2: f = 1 - rcp(d0*d1)          (3 trans)
//      cnt=3: full body with m-gate       (unchanged)
//    cnt=0 impossible: all edges inactive (c-r > 13 nats) => m_lo > 12
//    nats => classified cover. Overflow-safe: 2^x -> inf => rcp -> 0 =>
//    f -> 1e-6 clamp (deep inside) or 1 (far outside) — both correct.
//  * EXP2 DOMAIN: prep scales s by log2(e) (INV_SIGMA*1.4427); exp2f is
//    a bare v_exp_f32 (no hidden v_mul). All thresholds scaled to match:
//    T_CUT 12 -> 17.312, activity 13 nats -> 18.755.
//  * lazy sE1/sE2 loads (only the arms that need them issue the ds_read).
//  * dropped per-lane 'live' freeze: saturated lanes keep multiplying
//    (strictly MORE accurate); wave ballot-exit on acc > CUT retained.
// Staging/alive-vote/cover-fold/chunking: R20 exactly (best structure).
// LDS ~19.7KB -> 8 blocks/CU.
//
// Error budget vs 2e-2 tolerance (absmax floor 0.00390625 = one bf16 ulp
// since R5): cull skip <= 1538*e^-12 = 9.4e-3 worst-case; inactive-edge
// approx <= 2*e^-13 per face * ~220 band faces ~ 1e-3; branchless factor
// ~1e-7/face; product rounding ~1e-4.

#define IMG_S 320
#define N_FACES 1538
#define N_VERTS 778
#define N_BATCH 4
#define FP 1600            // padded face stride in ws
#define TILE 8
#define CHUNK_F 384        // faces per chunk (4 chunks: 384,384,384,386)
#define N_CHUNKS 4
#define MAXB 388           // LDS band capacity (>= max chunk size 386)
#define NWAVE 4
#define SCALE_S 144.2695041f   // 100 * log2(e): edges in log2-sigmoid domain
#define T_CUT_S 17.31234049f   // 12 nats in log2 units
#define T_ACT_S 18.75503553f   // 13 nats — per-edge activity threshold
#define ACC_CUT_P 2.2603294e-6f    // e^-13, product-domain saturation
#define LOG2_1EM6 -19.9315686f     // log2(1e-6)

__global__ __launch_bounds__(256)
void prep_faces(const float* __restrict__ verts,
                const int* __restrict__ faces,
                float4* __restrict__ gE0,
                float4* __restrict__ gE1,
                float4* __restrict__ gE2)
{
    const int f = blockIdx.x * 256 + threadIdx.x;
    const int b = blockIdx.z;
    if (f >= N_FACES) return;

    const float* vb = verts + (size_t)b * N_VERTS * 3;
    const int i0 = faces[f * 3 + 0];
    const int i1 = faces[f * 3 + 1];
    const int i2 = faces[f * 3 + 2];
    const float x0 = vb[i0 * 3 + 0], y0 = -vb[i0 * 3 + 1];
    const float x1 = vb[i1 * 3 + 0], y1 = -vb[i1 * 3 + 1];
    const float x2 = vb[i2 * 3 + 0], y2 = -vb[i2 * 3 + 1];

    // VERIFIED-EXACT (R4): fma-contracted area2 — do not change.
    const float dx1 = x1 - x0, dy1 = y1 - y0;
    const float dx2 = x2 - x0, dy2 = y2 - y0;
    const float area2 = __builtin_fmaf(dx1, dy2, -__fmul_rn(dy1, dx2));
    const float sgn = (area2 > 0.0f) ? 1.0f : ((area2 < 0.0f) ? -1.0f : 0.0f);

    const size_t o = (size_t)b * FP + f;
    {   // edge v0 -> v1
        const float ex = x1 - x0, ey = y1 - y0;
        const float s = sgn * SCALE_S / (sqrtf(ex * ex + ey * ey) + 1e-8f);
        gE0[o] = make_float4(-s * ey, s * ex, s * (ey * x0 - ex * y0), 0.0f);
    }
    {   // edge v1 -> v2
        const float ex = x2 - x1, ey = y2 - y1;
        const float s = sgn * SCALE_S / (sqrtf(ex * ex + ey * ey) + 1e-8f);
        gE1[o] = make_float4(-s * ey, s * ex, s * (ey * x1 - ex * y1), 0.0f);
    }
    {   // edge v2 -> v0
        const float ex = x0 - x2, ey = y0 - y2;
        const float s = sgn * SCALE_S / (sqrtf(ex * ex + ey * ey) + 1e-8f);
        gE2[o] = make_float4(-s * ey, s * ex, s * (ey * x2 - ex * y2), 0.0f);
    }
}

__global__ __launch_bounds__(256)
void silhouette_ws(const float4* __restrict__ gE0,
                   const float4* __restrict__ gE1,
                   const float4* __restrict__ gE2,
                   float* __restrict__ out)
{
    __shared__ float4 sE0[MAXB];   // first active edge (+count in .w)
    __shared__ float4 sE1[MAXB];   // second active edge (cnt>=2)
    __shared__ float4 sE2[MAXB];   // third edge (cnt==3)
    __shared__ float sAcc[256];
    __shared__ int sCount;
    __shared__ int sAlive;
    __shared__ int sCover;

    const int t    = threadIdx.x;
    const int wave = t >> 6;
    const int lane = t & 63;
    const int p    = t & 63;          // pixel id within 8x8 tile
    const int plx  = p & 7;
    const int ply  = p >> 3;
    const int b    = blockIdx.z;
    const int gx   = blockIdx.x * TILE + plx;
    const int gy   = blockIdx.y * TILE + ply;

    const float w  = 2.0f / IMG_S;
    const float px = (gx + 0.5f) * w - 1.0f;
    const float py = (gy + 0.5f) * w - 1.0f;
    const float cx = (blockIdx.x * TILE + 4) * w - 1.0f;
    const float cy = (blockIdx.y * TILE + 4) * w - 1.0f;
    const float rr = 3.5f * w;

    const float4* gb0 = gE0 + (size_t)b * FP;   // per-batch base
    const float4* gb1 = gE1 + (size_t)b * FP;
    const float4* gb2 = gE2 + (size_t)b * FP;

    float acc = 1.0f;   // product of (1-prob) over this wave's face subset
                        // (wave 0 also carries the cover factors)

    for (int c = 0; c < N_CHUNKS; ++c) {
        const int base = c * CHUNK_F;
        const int end  = (c == N_CHUNKS - 1) ? N_FACES : base + CHUNK_F;

        sAcc[t] = acc;
        if (t == 0) { sCount = 0; sAlive = 0; sCover = 0; }
        __syncthreads();   // B1: resets + partials visible

        const float tot = sAcc[p] * sAcc[p + 64] * sAcc[p + 128] * sAcc[p + 192];
        const bool alive = (tot > ACC_CUT_P);
        if (alive) sAlive = 1;               // benign same-value race
        __syncthreads();   // B2: vote final — break BEFORE staging
                           // (also fences prev chunk's sE reads from this
                           //  chunk's sE writes)

        if (sAlive == 0) break;   // uniform: every pixel saturated

        // ---- staging: classify faces, compact ACTIVE-EDGE payloads ----
        for (int fb = base; fb < end; fb += 256) {
            const int fc = fb + t;
            const bool vald = (fc < end);
            const int fcc = vald ? fc : (end - 1);
            const float4 e0 = gb0[fcc];      // coalesced vector loads
            const float4 e1 = gb1[fcc];
            const float4 e2 = gb2[fcc];
            const float c0 = fmaf(e0.x, cx, fmaf(e0.y, cy, e0.z));
            const float c1 = fmaf(e1.x, cx, fmaf(e1.y, cy, e1.z));
            const float c2 = fmaf(e2.x, cx, fmaf(e2.y, cy, e2.z));
            const float r0 = rr * (fabsf(e0.x) + fabsf(e0.y));
            const float r1 = rr * (fabsf(e1.x) + fabsf(e1.y));
            const float r2 = rr * (fabsf(e2.x) + fabsf(e2.y));
            const float m_hi = fminf(c0 + r0, fminf(c1 + r1, c2 + r2));
            const float m_lo = fminf(c0 - r0, fminf(c1 - r1, c2 - r2));
            const bool isCov  = vald && (m_lo > T_CUT_S);
            const bool isBand = vald && !isCov && (m_hi > -T_CUT_S);

            const unsigned long long mb = __ballot(isBand);
            int wbase = 0;
            if (lane == 0) {
                const int nw = __popcll(mb);
                if (nw) wbase = atomicAdd(&sCount, nw);
            }
            wbase = __shfl(wbase, 0);
            if (isBand) {
                const int pos = wbase + __popcll(mb & ((1ull << lane) - 1ull));
                // per-edge activity over the whole tile
                const bool a0 = (c0 - r0) <= T_ACT_S;
                const bool a1 = (c1 - r1) <= T_ACT_S;
                const bool a2 = (c2 - r2) <= T_ACT_S;
                const int cnt = (int)a0 + (int)a1 + (int)a2;   // 1..3
                // permute active edges first (see combo table in notes)
                float4 first  = a0 ? e0 : (a1 ? e1 : e2);
                const float4 second = a0 ? (a1 ? e1 : e2) : e2;
                first.w = __int_as_float(cnt);
                sE0[pos] = first;
                sE1[pos] = second;
                sE2[pos] = e2;
            }
            const unsigned long long mc = __ballot(isCov);
            if (lane == 0) {
                const int ncv = __popcll(mc);
                if (ncv) atomicAdd(&sCover, ncv);
            }
        }
        __syncthreads();   // B3: compaction + cover count final

        const float coverF = exp2f((float)sCover * LOG2_1EM6);
        if (wave == 0) acc *= coverF;

        const int n = sCount;
        int j = wave;
        while (j < n) {
            if (__ballot(acc > ACC_CUT_P) == 0ull) break;   // wave saturated
            const int j1 = j + NWAVE;
            const int j1c = (j1 < n) ? j1 : j;
            const float4 A0 = sE0[j];
            const float4 B0 = sE0[j1c];
            {   // iteration 0
                const float x0 = fmaf(A0.x, px, fmaf(A0.y, py, A0.z));
                const int cnt = __builtin_amdgcn_readfirstlane(
                                    __float_as_int(A0.w));
                if (cnt == 1) {
                    // f = 1 - sigmoid(x0) = 1/(1 + 2^x0)
                    acc *= fmaxf(__builtin_amdgcn_rcpf(1.0f + exp2f(x0)),
                                 1e-6f);
                } else {
                    const float4 A1 = sE1[j];
                    const float x1 = fmaf(A1.x, px, fmaf(A1.y, py, A1.z));
                    if (cnt == 2) {
                        const float d0 = 1.0f + exp2f(-x0);
                        const float d1 = 1.0f + exp2f(-x1);
                        acc *= fmaxf(
                            1.0f - __builtin_amdgcn_rcpf(d0 * d1), 1e-6f);
                    } else {
                        const float4 A2 = sE2[j];
                        const float x2 = fmaf(A2.x, px, fmaf(A2.y, py, A2.z));
                        const float m = fminf(x0, fminf(x1, x2));
                        if (m > -T_CUT_S) {
                            const float d0 = 1.0f + exp2f(-x0);
                            const float d1 = 1.0f + exp2f(-x1);
                            const float d2 = 1.0f + exp2f(-x2);
                            acc *= fmaxf(
                                1.0f - __builtin_amdgcn_rcpf(d0 * d1 * d2),
                                1e-6f);
                        }
                    }
                }
            }
            if (j1 < n) {   // iteration 1
                const float x0 = fmaf(B0.x, px, fmaf(B0.y, py, B0.z));
                const int cnt = __builtin_amdgcn_readfirstlane(
                                    __float_as_int(B0.w));
                if (cnt == 1) {
                    acc *= fmaxf(__builtin_amdgcn_rcpf(1.0f + exp2f(x0)),
                                 1e-6f);
                } else {
                    const float4 B1 = sE1[j1c];
                    const float x1 = fmaf(B1.x, px, fmaf(B1.y, py, B1.z));
                    if (cnt == 2) {
                        const float d0 = 1.0f + exp2f(-x0);
                        const float d1 = 1.0f + exp2f(-x1);
                        acc *= fmaxf(
                            1.0f - __builtin_amdgcn_rcpf(d0 * d1), 1e-6f);
                    } else {
                        const float4 B2 = sE2[j1c];
                        const float x2 = fmaf(B2.x, px, fmaf(B2.y, py, B2.z));
                        const float m = fminf(x0, fminf(x1, x2));
                        if (m > -T_CUT_S) {
                            const float d0 = 1.0f + exp2f(-x0);
                            const float d1 = 1.0f + exp2f(-x1);
                            const float d2 = 1.0f + exp2f(-x2);
                            acc *= fmaxf(
                                1.0f - __builtin_amdgcn_rcpf(d0 * d1 * d2),
                                1e-6f);
                        }
                    }
                }
            }
            j += 2 * NWAVE;
        }
        // no B4: next chunk's sE writes happen after its B2, which every
        // wave passes only after finishing this j-loop.
    }

    // final reduction + output (loop exits are block-uniform)
    sAcc[t] = acc;
    __syncthreads();
    if (t < 64) {
        const float tot = sAcc[p] * sAcc[p + 64] * sAcc[p + 128] * sAcc[p + 192];
        out[(size_t)b * (IMG_S * IMG_S) + (size_t)gy * IMG_S + gx] = 1.0f - tot;
    }
}

extern "C" void kernel_launch(void* const* d_in, const int* in_sizes, int n_in,
                              void* d_out, int out_size, void* d_ws, size_t ws_size,
                              hipStream_t stream) {
    const float* verts = (const float*)d_in[0];
    const int* faces = (const int*)d_in[1];
    float* out = (float*)d_out;

    // ws layout: 3 arrays of float4[N_BATCH * FP]  (3 * 4*1600*16B = 307 KB)
    float4* gE0 = (float4*)d_ws;
    float4* gE1 = gE0 + (size_t)N_BATCH * FP;
    float4* gE2 = gE1 + (size_t)N_BATCH * FP;

    dim3 pgrid((N_FACES + 255) / 256, 1, N_BATCH);
    prep_faces<<<pgrid, 256, 0, stream>>>(verts, faces, gE0, gE1, gE2);

    dim3 grid(IMG_S / TILE, IMG_S / TILE, N_BATCH);
    silhouette_ws<<<grid, 256, 0, stream>>>(gE0, gE1, gE2, out);
}

// Round 6
// 128.770 us; speedup vs baseline: 1.0416x; 1.0416x over previous
//
#include <hip/hip_runtime.h>
#include <math.h>

// Soft silhouette renderer — R24 = R20 structure + active-edge
// specialization done by SORTING (two compaction classes) instead of
// R23's branching, + exp2-domain coefficients.
// verts: (4, 778, 3) f32   faces: (1538, 3) i32   out: (4, 320, 320) f32
//
// Verified-exact math core (R4, absmax 0.0):
//   area2 = fma(dx1, dy2, -round(dy1*dx2)) — matches the reference
//   evaluator's contraction; degenerate faces (sgn=0 -> 1/8 veil, i1==i2
//   sliver -> sigma=1/2 ridge) fall out of the generic edge code.
//   (Scaling s by log2e preserves sign/zero structure — area2 untouched.)
//
// R23 post-mortem (134us, silhouette_ws 88us): two compounding failures.
//  (a) WRITE_SIZE 101MB + VGPR_Count 28 => register allocator spilled the
//      float4s held across the 3-deep divergent lazy-load branch nest to
//      SCRATCH (writes stream to HBM; reads hit L2 -> FETCH only 11MB).
//  (b) lazy sE loads serialized LDS latency: ds_read A0 -> wait -> branch
//      on A0.w -> ds_read A1 -> wait -> ... ~3x120cy/face vs R20's one
//      batched issue. VALUBusy 25%, occ 55% = latency-bound.
// The SPECIALIZATION itself is good (absmax improved to 0.00195; trans
// count is the j-loop bottleneck per R22's arithmetic: 4 quarter-rate
// trans = 32 of ~60 issue-cy/face).
//
// R24 keeps the trans reduction but with flat control flow:
//  * staging classifies each band face by active-edge count over the tile
//    (edge i active iff c_i - r_i <= 13 nats; inactive sigmoids are 1
//    within 2.3e-6) and compacts into ONE shared LDS buffer:
//      singles (cnt<=1): the 1 active float4, bottom-up at sBuf[pos]
//      triples (cnt>=2): all 3 float4s, top-down at sBuf[3*MAXB-3*(pos+1)]
//    capacity: n1 + 3*n3 <= 386 + 2*386 = 1158 < 1164 slots — no overlap.
//    (cnt==0 is near-impossible (=> cover), but maps correctly through the
//    singles path: x huge positive -> f -> 1e-6 clamp = reference's clip.)
//  * j-loop = two UNIFORM branchless phases, loads issued up-front:
//      phase 1 singles: x=fma; acc *= max(rcp(1+2^x),1e-6)   (2 trans)
//      phase 2 triples: exact R20 body in exp2 domain, 3 loads batched,
//                       per-lane m-gate (execz skips whole-wave-outside)
//    cnt=2 faces now get EXACT 3-edge math (less approx than R23).
//  * exp2 domain: prep scales s by log2(e); exp2f = bare v_exp_f32.
// Alive-vote / cover-fold / chunking / 2x unroll: R20 exactly.
// LDS: sBuf 1164*16B = 18.6KB + sAcc 1KB ~= 19.7KB -> 8 blocks/CU.
//
// Error budget vs 2e-2 tolerance (absmax floor ~one bf16 ulp since R5):
// cull skip <= 1538*e^-12 = 9.4e-3 worst-case; single-path inactive-edge
// approx <= 2*e^-13/face * ~150 faces ~ 7e-4; saturation cut 2.3e-6;
// product rounding ~1e-4 (incl. compaction reorder).

#define IMG_S 320
#define N_FACES 1538
#define N_VERTS 778
#define N_BATCH 4
#define FP 1600            // padded face stride in ws
#define TILE 8
#define CHUNK_F 384        // faces per chunk (4 chunks: 384,384,384,386)
#define N_CHUNKS 4
#define MAXB 388           // per-chunk face capacity (>= max chunk 386)
#define NWAVE 4
#define SCALE_S 144.2695041f   // 100 * log2(e): edges in log2-sigmoid domain
#define T_CUT_S 17.31234049f   // 12 nats in log2 units
#define T_ACT_S 18.75503553f   // 13 nats — per-edge activity threshold
#define ACC_CUT_P 2.2603294e-6f    // e^-13, product-domain saturation
#define LOG2_1EM6 -19.9315686f     // log2(1e-6)

__global__ __launch_bounds__(256)
void prep_faces(const float* __restrict__ verts,
                const int* __restrict__ faces,
                float4* __restrict__ gE0,
                float4* __restrict__ gE1,
                float4* __restrict__ gE2)
{
    const int f = blockIdx.x * 256 + threadIdx.x;
    const int b = blockIdx.z;
    if (f >= N_FACES) return;

    const float* vb = verts + (size_t)b * N_VERTS * 3;
    const int i0 = faces[f * 3 + 0];
    const int i1 = faces[f * 3 + 1];
    const int i2 = faces[f * 3 + 2];
    const float x0 = vb[i0 * 3 + 0], y0 = -vb[i0 * 3 + 1];
    const float x1 = vb[i1 * 3 + 0], y1 = -vb[i1 * 3 + 1];
    const float x2 = vb[i2 * 3 + 0], y2 = -vb[i2 * 3 + 1];

    // VERIFIED-EXACT (R4): fma-contracted area2 — do not change.
    const float dx1 = x1 - x0, dy1 = y1 - y0;
    const float dx2 = x2 - x0, dy2 = y2 - y0;
    const float area2 = __builtin_fmaf(dx1, dy2, -__fmul_rn(dy1, dx2));
    const float sgn = (area2 > 0.0f) ? 1.0f : ((area2 < 0.0f) ? -1.0f : 0.0f);

    const size_t o = (size_t)b * FP + f;
    {   // edge v0 -> v1
        const float ex = x1 - x0, ey = y1 - y0;
        const float s = sgn * SCALE_S / (sqrtf(ex * ex + ey * ey) + 1e-8f);
        gE0[o] = make_float4(-s * ey, s * ex, s * (ey * x0 - ex * y0), 0.0f);
    }
    {   // edge v1 -> v2
        const float ex = x2 - x1, ey = y2 - y1;
        const float s = sgn * SCALE_S / (sqrtf(ex * ex + ey * ey) + 1e-8f);
        gE1[o] = make_float4(-s * ey, s * ex, s * (ey * x1 - ex * y1), 0.0f);
    }
    {   // edge v2 -> v0
        const float ex = x0 - x2, ey = y0 - y2;
        const float s = sgn * SCALE_S / (sqrtf(ex * ex + ey * ey) + 1e-8f);
        gE2[o] = make_float4(-s * ey, s * ex, s * (ey * x2 - ex * y2), 0.0f);
    }
}

__global__ __launch_bounds__(256)
void silhouette_ws(const float4* __restrict__ gE0,
                   const float4* __restrict__ gE1,
                   const float4* __restrict__ gE2,
                   float* __restrict__ out)
{
    __shared__ float4 sBuf[3 * MAXB];   // singles bottom-up, triples top-down
    __shared__ float sAcc[256];
    __shared__ int sCount1;
    __shared__ int sCount3;
    __shared__ int sAlive;
    __shared__ int sCover;

    const int t    = threadIdx.x;
    const int wave = t >> 6;
    const int lane = t & 63;
    const int p    = t & 63;          // pixel id within 8x8 tile
    const int plx  = p & 7;
    const int ply  = p >> 3;
    const int b    = blockIdx.z;
    const int gx   = blockIdx.x * TILE + plx;
    const int gy   = blockIdx.y * TILE + ply;

    const float w  = 2.0f / IMG_S;
    const float px = (gx + 0.5f) * w - 1.0f;
    const float py = (gy + 0.5f) * w - 1.0f;
    const float cx = (blockIdx.x * TILE + 4) * w - 1.0f;
    const float cy = (blockIdx.y * TILE + 4) * w - 1.0f;
    const float rr = 3.5f * w;

    const float4* gb0 = gE0 + (size_t)b * FP;   // per-batch base
    const float4* gb1 = gE1 + (size_t)b * FP;
    const float4* gb2 = gE2 + (size_t)b * FP;

    float acc = 1.0f;   // product of (1-prob) over this wave's face subset
                        // (wave 0 also carries the cover factors)

    for (int c = 0; c < N_CHUNKS; ++c) {
        const int base = c * CHUNK_F;
        const int end  = (c == N_CHUNKS - 1) ? N_FACES : base + CHUNK_F;

        sAcc[t] = acc;
        if (t == 0) { sCount1 = 0; sCount3 = 0; sAlive = 0; sCover = 0; }
        __syncthreads();   // B1: resets + partials visible

        const float tot = sAcc[p] * sAcc[p + 64] * sAcc[p + 128] * sAcc[p + 192];
        const bool alive = (tot > ACC_CUT_P);
        if (alive) sAlive = 1;               // benign same-value race
        __syncthreads();   // B2: vote final — break BEFORE staging
                           // (also fences prev chunk's sBuf reads from
                           //  this chunk's sBuf writes)

        if (sAlive == 0) break;   // uniform: every pixel saturated

        // ---- staging: classify, split into singles/triples, compact ----
        for (int fb = base; fb < end; fb += 256) {
            const int fc = fb + t;
            const bool vald = (fc < end);
            const int fcc = vald ? fc : (end - 1);
            const float4 e0 = gb0[fcc];      // coalesced vector loads
            const float4 e1 = gb1[fcc];
            const float4 e2 = gb2[fcc];
            const float c0 = fmaf(e0.x, cx, fmaf(e0.y, cy, e0.z));
            const float c1 = fmaf(e1.x, cx, fmaf(e1.y, cy, e1.z));
            const float c2 = fmaf(e2.x, cx, fmaf(e2.y, cy, e2.z));
            const float r0 = rr * (fabsf(e0.x) + fabsf(e0.y));
            const float r1 = rr * (fabsf(e1.x) + fabsf(e1.y));
            const float r2 = rr * (fabsf(e2.x) + fabsf(e2.y));
            const float m_hi = fminf(c0 + r0, fminf(c1 + r1, c2 + r2));
            const float m_lo = fminf(c0 - r0, fminf(c1 - r1, c2 - r2));
            const bool isCov  = vald && (m_lo > T_CUT_S);
            const bool isBand = vald && !isCov && (m_hi > -T_CUT_S);

            const bool a0 = (c0 - r0) <= T_ACT_S;   // edge active over tile
            const bool a1 = (c1 - r1) <= T_ACT_S;
            const bool a2 = (c2 - r2) <= T_ACT_S;
            const int cnt = (int)a0 + (int)a1 + (int)a2;
            const bool isS = isBand && (cnt <= 1);
            const bool isT = isBand && (cnt >= 2);

            {   // singles compaction (bottom-up)
                const unsigned long long ms = __ballot(isS);
                int wb = 0;
                if (lane == 0) {
                    const int nw = __popcll(ms);
                    if (nw) wb = atomicAdd(&sCount1, nw);
                }
                wb = __shfl(wb, 0);
                if (isS) {
                    const int pos = wb + __popcll(ms & ((1ull << lane) - 1ull));
                    sBuf[pos] = a0 ? e0 : (a1 ? e1 : e2);
                }
            }
            {   // triples compaction (top-down)
                const unsigned long long mt = __ballot(isT);
                int wb = 0;
                if (lane == 0) {
                    const int nw = __popcll(mt);
                    if (nw) wb = atomicAdd(&sCount3, nw);
                }
                wb = __shfl(wb, 0);
                if (isT) {
                    const int pos = wb + __popcll(mt & ((1ull << lane) - 1ull));
                    const int bix = 3 * MAXB - 3 * (pos + 1);
                    sBuf[bix + 0] = e0;
                    sBuf[bix + 1] = e1;
                    sBuf[bix + 2] = e2;
                }
            }
            const unsigned long long mc = __ballot(isCov);
            if (lane == 0) {
                const int ncv = __popcll(mc);
                if (ncv) atomicAdd(&sCover, ncv);
            }
        }
        __syncthreads();   // B3: compaction + cover count final

        const float coverF = exp2f((float)sCover * LOG2_1EM6);
        if (wave == 0) acc *= coverF;

        // ---- phase 1: singles — branchless, 2 trans/face ----
        const int n1 = sCount1;
        int j = wave;
        while (j < n1) {
            if (__ballot(acc > ACC_CUT_P) == 0ull) break;   // wave saturated
            const int j1 = j + NWAVE;
            const int j1c = (j1 < n1) ? j1 : j;
            const float4 A = sBuf[j];        // both loads issued up-front
            const float4 B = sBuf[j1c];
            {
                const float x = fmaf(A.x, px, fmaf(A.y, py, A.z));
                acc *= fmaxf(__builtin_amdgcn_rcpf(1.0f + exp2f(x)), 1e-6f);
            }
            if (j1 < n1) {
                const float x = fmaf(B.x, px, fmaf(B.y, py, B.z));
                acc *= fmaxf(__builtin_amdgcn_rcpf(1.0f + exp2f(x)), 1e-6f);
            }
            j += 2 * NWAVE;
        }

        // ---- phase 2: triples — exact R20 body (exp2 domain) ----
        const int n3 = sCount3;
        j = wave;
        while (j < n3) {
            if (__ballot(acc > ACC_CUT_P) == 0ull) break;   // wave saturated
            const int j1 = j + NWAVE;
            const int j1c = (j1 < n3) ? j1 : j;
            const int bx0 = 3 * MAXB - 3 * (j + 1);
            const int bx1 = 3 * MAXB - 3 * (j1c + 1);
            // all 6 loads issued before any compute
            const float4 A0 = sBuf[bx0], A1 = sBuf[bx0 + 1], A2 = sBuf[bx0 + 2];
            const float4 B0 = sBuf[bx1], B1 = sBuf[bx1 + 1], B2 = sBuf[bx1 + 2];
            {   // iteration 0
                const float xa = fmaf(A0.x, px, fmaf(A0.y, py, A0.z));
                const float xb = fmaf(A1.x, px, fmaf(A1.y, py, A1.z));
                const float xc = fmaf(A2.x, px, fmaf(A2.y, py, A2.z));
                const float m = fminf(xa, fminf(xb, xc));
                if (m > -T_CUT_S) {
                    const float da = 1.0f + exp2f(-xa);
                    const float db = 1.0f + exp2f(-xb);
                    const float dc = 1.0f + exp2f(-xc);
                    acc *= fmaxf(
                        1.0f - __builtin_amdgcn_rcpf(da * db * dc), 1e-6f);
                }
            }
            if (j1 < n3) {   // iteration 1
                const float xa = fmaf(B0.x, px, fmaf(B0.y, py, B0.z));
                const float xb = fmaf(B1.x, px, fmaf(B1.y, py, B1.z));
                const float xc = fmaf(B2.x, px, fmaf(B2.y, py, B2.z));
                const float m = fminf(xa, fminf(xb, xc));
                if (m > -T_CUT_S) {
                    const float da = 1.0f + exp2f(-xa);
                    const float db = 1.0f + exp2f(-xb);
                    const float dc = 1.0f + exp2f(-xc);
                    acc *= fmaxf(
                        1.0f - __builtin_amdgcn_rcpf(da * db * dc), 1e-6f);
                }
            }
            j += 2 * NWAVE;
        }
        // no B4: next chunk's sBuf writes happen after its B2, which every
        // wave passes only after finishing both phases.
    }

    // final reduction + output (loop exits are block-uniform)
    sAcc[t] = acc;
    __syncthreads();
    if (t < 64) {
        const float tot = sAcc[p] * sAcc[p + 64] * sAcc[p + 128] * sAcc[p + 192];
        out[(size_t)b * (IMG_S * IMG_S) + (size_t)gy * IMG_S + gx] = 1.0f - tot;
    }
}

extern "C" void kernel_launch(void* const* d_in, const int* in_sizes, int n_in,
                              void* d_out, int out_size, void* d_ws, size_t ws_size,
                              hipStream_t stream) {
    const float* verts = (const float*)d_in[0];
    const int* faces = (const int*)d_in[1];
    float* out = (float*)d_out;

    // ws layout: 3 arrays of float4[N_BATCH * FP]  (3 * 4*1600*16B = 307 KB)
    float4* gE0 = (float4*)d_ws;
    float4* gE1 = gE0 + (size_t)N_BATCH * FP;
    float4* gE2 = gE1 + (size_t)N_BATCH * FP;

    dim3 pgrid((N_FACES + 255) / 256, 1, N_BATCH);
    prep_faces<<<pgrid, 256, 0, stream>>>(verts, faces, gE0, gE1, gE2);

    dim3 grid(IMG_S / TILE, IMG_S / TILE, N_BATCH);
    silhouette_ws<<<grid, 256, 0, stream>>>(gE0, gE1, gE2, out);
}

// Round 8
// 128.297 us; speedup vs baseline: 1.0455x; 1.0037x over previous
//
#include <hip/hip_runtime.h>
#include <math.h>

// Soft silhouette renderer — R25 (resubmit; round-7 bench was an infra
// failure: "MI355X container failed twice" — no kernel signal).
// R25 = R20 VERBATIM structure + singles/triples sort, all math kept in
// R20's e-domain with __expf (native v_exp) ONLY.
// verts: (4, 778, 3) f32   faces: (1538, 3) i32   out: (4, 320, 320) f32
//
// Verified-exact math core (R4, absmax 0.0):
//   area2 = fma(dx1, dy2, -round(dy1*dx2)) — matches the reference
//   evaluator's contraction; degenerate faces (sgn=0 -> 1/8 veil, i1==i2
//   sliver -> sigma=1/2 ridge) fall out of the generic edge code.
//
// R24 post-mortem: flat control flow did NOT fix the regression
// (silhouette still 80us, WRITE_SIZE still 117MB, VALUBusy 25%) — so the
// R23 "branch-nest spill" theory was wrong. The factor shared by BOTH
// regressing kernels (R23, R24) and absent from every fast kernel is
// exp2f(): without fast-math it lowers to __ocml_exp2_f32 (denormal-
// handling path), not bare v_exp_f32 — implicated in the ~70B/thread of
// scratch writes and the latency-bound profile. R20's __expf is native
// and always inline.
//
// R25 isolates the remaining untested idea (the sort) from the exp2f
// poison: R20 code verbatim — e-domain coefficients (INV_SIGMA=100),
// __expf everywhere, live/alive gating, chunking, 2x unroll — plus ONLY:
//  * staging classifies active-edge count over the tile (edge i active
//    iff c_i - r_i <= 13 nats; inactive sigmoids are 1 within 2.3e-6)
//    and compacts into one LDS buffer: singles (cnt<=1: the 1 active
//    float4) bottom-up, triples (cnt>=2: all 3) top-down.
//    cnt=0 impossible in band: all c-r > 13 => m_lo > 12 => cover.
//    capacity n1 + 3*n3 <= 386 + 2*386 = 1158 <= 1163: no overlap.
//  * j-loop phase 1 (singles): acc *= max(rcp(1+__expf(x)), 1e-6)
//    — 2 trans/face vs 4; ~70% of band faces are singles.
//  * j-loop phase 2 (triples): R20's exact branchless body, 4 trans.
// If this regresses like R23/R24, the sort is the problem -> pure R20.
// LDS: sBuf 1164*16B + sAcc 1KB ~= 19.7KB -> 8 blocks/CU, as R20.
//
// Error budget vs 2e-2 tolerance (absmax floor 0.00390625 = one bf16 ulp
// since R5): cull skip <= 1538*e^-12 = 9.4e-3 worst-case; inactive-edge
// approx <= 2*e^-13/face * ~150 singles ~ 7e-4; branchless factor
// ~1e-7/face; saturation cut 2.3e-6; product rounding ~1e-4.

#define IMG_S 320
#define N_FACES 1538
#define N_VERTS 778
#define N_BATCH 4
#define FP 1600            // padded face stride in ws
#define TILE 8
#define CHUNK_F 384        // faces per chunk (4 chunks: 384,384,384,386)
#define N_CHUNKS 4
#define MAXB 388           // per-chunk face capacity (>= max chunk 386)
#define NWAVE 4
#define INV_SIGMA 100.0f
#define T_CUT 12.0f
#define T_ACT 13.0f        // per-edge activity threshold (nats)
#define ACC_CUT_P 2.2603294e-6f    // e^-13, product-domain saturation
#define LOG2_1EM6 -19.9315686f     // log2(1e-6)

__global__ __launch_bounds__(256)
void prep_faces(const float* __restrict__ verts,
                const int* __restrict__ faces,
                float4* __restrict__ gE0,
                float4* __restrict__ gE1,
                float4* __restrict__ gE2)
{
    const int f = blockIdx.x * 256 + threadIdx.x;
    const int b = blockIdx.z;
    if (f >= N_FACES) return;

    const float* vb = verts + (size_t)b * N_VERTS * 3;
    const int i0 = faces[f * 3 + 0];
    const int i1 = faces[f * 3 + 1];
    const int i2 = faces[f * 3 + 2];
    const float x0 = vb[i0 * 3 + 0], y0 = -vb[i0 * 3 + 1];
    const float x1 = vb[i1 * 3 + 0], y1 = -vb[i1 * 3 + 1];
    const float x2 = vb[i2 * 3 + 0], y2 = -vb[i2 * 3 + 1];

    // VERIFIED-EXACT (R4): fma-contracted area2 — do not change.
    const float dx1 = x1 - x0, dy1 = y1 - y0;
    const float dx2 = x2 - x0, dy2 = y2 - y0;
    const float area2 = __builtin_fmaf(dx1, dy2, -__fmul_rn(dy1, dx2));
    const float sgn = (area2 > 0.0f) ? 1.0f : ((area2 < 0.0f) ? -1.0f : 0.0f);

    const size_t o = (size_t)b * FP + f;
    {   // edge v0 -> v1
        const float ex = x1 - x0, ey = y1 - y0;
        const float s = sgn * INV_SIGMA / (sqrtf(ex * ex + ey * ey) + 1e-8f);
        gE0[o] = make_float4(-s * ey, s * ex, s * (ey * x0 - ex * y0), 0.0f);
    }
    {   // edge v1 -> v2
        const float ex = x2 - x1, ey = y2 - y1;
        const float s = sgn * INV_SIGMA / (sqrtf(ex * ex + ey * ey) + 1e-8f);
        gE1[o] = make_float4(-s * ey, s * ex, s * (ey * x1 - ex * y1), 0.0f);
    }
    {   // edge v2 -> v0
        const float ex = x0 - x2, ey = y0 - y2;
        const float s = sgn * INV_SIGMA / (sqrtf(ex * ex + ey * ey) + 1e-8f);
        gE2[o] = make_float4(-s * ey, s * ex, s * (ey * x2 - ex * y2), 0.0f);
    }
}

__global__ __launch_bounds__(256)
void silhouette_ws(const float4* __restrict__ gE0,
                   const float4* __restrict__ gE1,
                   const float4* __restrict__ gE2,
                   float* __restrict__ out)
{
    __shared__ float4 sBuf[3 * MAXB];   // singles bottom-up, triples top-down
    __shared__ float sAcc[256];
    __shared__ int sCount1;
    __shared__ int sCount3;
    __shared__ int sAlive;
    __shared__ int sCover;

    const int t    = threadIdx.x;
    const int wave = t >> 6;
    const int lane = t & 63;
    const int p    = t & 63;          // pixel id within 8x8 tile
    const int plx  = p & 7;
    const int ply  = p >> 3;
    const int b    = blockIdx.z;
    const int gx   = blockIdx.x * TILE + plx;
    const int gy   = blockIdx.y * TILE + ply;

    const float w  = 2.0f / IMG_S;
    const float px = (gx + 0.5f) * w - 1.0f;
    const float py = (gy + 0.5f) * w - 1.0f;
    const float cx = (blockIdx.x * TILE + 4) * w - 1.0f;
    const float cy = (blockIdx.y * TILE + 4) * w - 1.0f;
    const float rr = 3.5f * w;

    const float4* gb0 = gE0 + (size_t)b * FP;   // per-batch base
    const float4* gb1 = gE1 + (size_t)b * FP;
    const float4* gb2 = gE2 + (size_t)b * FP;

    float acc = 1.0f;   // product of (1-prob) over this wave's face subset
                        // (wave 0 also carries the cover factors)

    for (int c = 0; c < N_CHUNKS; ++c) {
        const int base = c * CHUNK_F;
        const int end  = (c == N_CHUNKS - 1) ? N_FACES : base + CHUNK_F;

        sAcc[t] = acc;
        if (t == 0) { sCount1 = 0; sCount3 = 0; sAlive = 0; sCover = 0; }
        __syncthreads();   // B1: resets + partials visible

        const float tot = sAcc[p] * sAcc[p + 64] * sAcc[p + 128] * sAcc[p + 192];
        const bool alive = (tot > ACC_CUT_P);
        if (alive) sAlive = 1;               // benign same-value race
        __syncthreads();   // B2: vote final — break BEFORE staging
                           // (also fences prev chunk's sBuf reads from
                           //  this chunk's sBuf writes)

        if (sAlive == 0) break;   // uniform: every pixel saturated

        // ---- staging: classify, split into singles/triples, compact ----
        for (int fb = base; fb < end; fb += 256) {
            const int fc = fb + t;
            const bool vald = (fc < end);
            const int fcc = vald ? fc : (end - 1);
            const float4 e0 = gb0[fcc];      // coalesced vector loads
            const float4 e1 = gb1[fcc];
            const float4 e2 = gb2[fcc];
            const float c0 = fmaf(e0.x, cx, fmaf(e0.y, cy, e0.z));
            const float c1 = fmaf(e1.x, cx, fmaf(e1.y, cy, e1.z));
            const float c2 = fmaf(e2.x, cx, fmaf(e2.y, cy, e2.z));
            const float r0 = rr * (fabsf(e0.x) + fabsf(e0.y));
            const float r1 = rr * (fabsf(e1.x) + fabsf(e1.y));
            const float r2 = rr * (fabsf(e2.x) + fabsf(e2.y));
            const float m_hi = fminf(c0 + r0, fminf(c1 + r1, c2 + r2));
            const float m_lo = fminf(c0 - r0, fminf(c1 - r1, c2 - r2));
            const bool isCov  = vald && (m_lo > T_CUT);
            const bool isBand = vald && !isCov && (m_hi > -T_CUT);

            const bool a0 = (c0 - r0) <= T_ACT;   // edge active over tile
            const bool a1 = (c1 - r1) <= T_ACT;
            const bool a2 = (c2 - r2) <= T_ACT;
            const int cnt = (int)a0 + (int)a1 + (int)a2;
            const bool isS = isBand && (cnt <= 1);
            const bool isT = isBand && (cnt >= 2);

            {   // singles compaction (bottom-up)
                const unsigned long long ms = __ballot(isS);
                int wb = 0;
                if (lane == 0) {
                    const int nw = __popcll(ms);
                    if (nw) wb = atomicAdd(&sCount1, nw);
                }
                wb = __shfl(wb, 0);
                if (isS) {
                    const int pos = wb + __popcll(ms & ((1ull << lane) - 1ull));
                    sBuf[pos] = a0 ? e0 : (a1 ? e1 : e2);
                }
            }
            {   // triples compaction (top-down)
                const unsigned long long mt = __ballot(isT);
                int wb = 0;
                if (lane == 0) {
                    const int nw = __popcll(mt);
                    if (nw) wb = atomicAdd(&sCount3, nw);
                }
                wb = __shfl(wb, 0);
                if (isT) {
                    const int pos = wb + __popcll(mt & ((1ull << lane) - 1ull));
                    const int bix = 3 * MAXB - 3 * (pos + 1);
                    sBuf[bix + 0] = e0;
                    sBuf[bix + 1] = e1;
                    sBuf[bix + 2] = e2;
                }
            }
            const unsigned long long mc = __ballot(isCov);
            if (lane == 0) {
                const int ncv = __popcll(mc);
                if (ncv) atomicAdd(&sCover, ncv);
            }
        }
        __syncthreads();   // B3: compaction + cover count final

        const float coverF = exp2f((float)sCover * LOG2_1EM6);
        bool live = alive && (acc * coverF > ACC_CUT_P);
        if (wave == 0) acc *= coverF;

        // ---- phase 1: singles — 2 trans/face, R20 gating ----
        const int n1 = sCount1;
        int j = wave;
        while (j < n1) {
            if (__ballot(live) == 0ull) break;   // whole wave saturated
            const int j1 = j + NWAVE;
            const int j1c = (j1 < n1) ? j1 : j;
            const float4 A = sBuf[j];        // both loads issued up-front
            const float4 B = sBuf[j1c];
            {
                const float x = fmaf(A.x, px, fmaf(A.y, py, A.z));
                if (live) {
                    acc *= fmaxf(__builtin_amdgcn_rcpf(1.0f + __expf(x)),
                                 1e-6f);
                    live = (acc > ACC_CUT_P);
                }
            }
            if (j1 < n1) {
                const float x = fmaf(B.x, px, fmaf(B.y, py, B.z));
                if (live) {
                    acc *= fmaxf(__builtin_amdgcn_rcpf(1.0f + __expf(x)),
                                 1e-6f);
                    live = (acc > ACC_CUT_P);
                }
            }
            j += 2 * NWAVE;
        }

        // ---- phase 2: triples — R20's exact branchless body ----
        const int n3 = sCount3;
        j = wave;
        while (j < n3) {
            if (__ballot(live) == 0ull) break;   // whole wave saturated
            const int j1 = j + NWAVE;
            const int j1c = (j1 < n3) ? j1 : j;
            const int bx0 = 3 * MAXB - 3 * (j + 1);
            const int bx1 = 3 * MAXB - 3 * (j1c + 1);
            // all 6 loads issued before any compute
            const float4 A0 = sBuf[bx0], A1 = sBuf[bx0 + 1], A2 = sBuf[bx0 + 2];
            const float4 B0 = sBuf[bx1], B1 = sBuf[bx1 + 1], B2 = sBuf[bx1 + 2];
            {   // iteration 0
                const float xa = fmaf(A0.x, px, fmaf(A0.y, py, A0.z));
                const float xb = fmaf(A1.x, px, fmaf(A1.y, py, A1.z));
                const float xc = fmaf(A2.x, px, fmaf(A2.y, py, A2.z));
                const float m = fminf(xa, fminf(xb, xc));
                if (live && m > -T_CUT) {
                    const float da = 1.0f + __expf(-xa);
                    const float db = 1.0f + __expf(-xb);
                    const float dc = 1.0f + __expf(-xc);
                    const float f = fmaxf(
                        1.0f - __builtin_amdgcn_rcpf(da * db * dc), 1e-6f);
                    acc *= f;
                    live = (acc > ACC_CUT_P);
                }
            }
            if (j1 < n3) {   // iteration 1
                const float xa = fmaf(B0.x, px, fmaf(B0.y, py, B0.z));
                const float xb = fmaf(B1.x, px, fmaf(B1.y, py, B1.z));
                const float xc = fmaf(B2.x, px, fmaf(B2.y, py, B2.z));
                const float m = fminf(xa, fminf(xb, xc));
                if (live && m > -T_CUT) {
                    const float da = 1.0f + __expf(-xa);
                    const float db = 1.0f + __expf(-xb);
                    const float dc = 1.0f + __expf(-xc);
                    const float f = fmaxf(
                        1.0f - __builtin_amdgcn_rcpf(da * db * dc), 1e-6f);
                    acc *= f;
                    live = (acc > ACC_CUT_P);
                }
            }
            j += 2 * NWAVE;
        }
        // no B4: next chunk's sBuf writes happen after its B2, which every
        // wave passes only after finishing both phases.
    }

    // final reduction + output (loop exits are block-uniform)
    sAcc[t] = acc;
    __syncthreads();
    if (t < 64) {
        const float tot = sAcc[p] * sAcc[p + 64] * sAcc[p + 128] * sAcc[p + 192];
        out[(size_t)b * (IMG_S * IMG_S) + (size_t)gy * IMG_S + gx] = 1.0f - tot;
    }
}

extern "C" void kernel_launch(void* const* d_in, const int* in_sizes, int n_in,
                              void* d_out, int out_size, void* d_ws, size_t ws_size,
                              hipStream_t stream) {
    const float* verts = (const float*)d_in[0];
    const int* faces = (const int*)d_in[1];
    float* out = (float*)d_out;

    // ws layout: 3 arrays of float4[N_BATCH * FP]  (3 * 4*1600*16B = 307 KB)
    float4* gE0 = (float4*)d_ws;
    float4* gE1 = gE0 + (size_t)N_BATCH * FP;
    float4* gE2 = gE1 + (size_t)N_BATCH * FP;

    dim3 pgrid((N_FACES + 255) / 256, 1, N_BATCH);
    prep_faces<<<pgrid, 256, 0, stream>>>(verts, faces, gE0, gE1, gE2);

    dim3 grid(IMG_S / TILE, IMG_S / TILE, N_BATCH);
    silhouette_ws<<<grid, 256, 0, stream>>>(gE0, gE1, gE2, out);
}

// Round 9
// 85.895 us; speedup vs baseline: 1.5615x; 1.4936x over previous
//
#include <hip/hip_runtime.h>
#include <math.h>

// Soft silhouette renderer — R26 = R25 with the aggregate float4 ternary
// in staging decomposed into SCALAR component selects (v_cndmask), fixing
// the scratch-demotion that poisoned R23/R24/R25.
// verts: (4, 778, 3) f32   faces: (1538, 3) i32   out: (4, 320, 320) f32
//
// Verified-exact math core (R4, absmax 0.0):
//   area2 = fma(dx1, dy2, -round(dy1*dx2)) — matches the reference
//   evaluator's contraction; degenerate faces (sgn=0 -> 1/8 veil, i1==i2
//   sliver -> sigma=1/2 ridge) fall out of the generic edge code.
//
// R25 post-mortem: e-domain __expf did NOT fix it (silhouette 78us,
// WRITE_SIZE 117MB, VGPR 28, VALUBusy 21%) — exp2f theory dead. The one
// construct common to R23/R24/R25 and absent from every fast kernel is
// the AGGREGATE conditional select:
//     sBuf[pos] = a0 ? e0 : (a1 ? e1 : e2);
// A 16-byte aggregate ternary with runtime predicates is the rule-#20
// shape: lowered as local array + dynamic index -> SCRATCH. It explains
// every anomaly at once: VGPR 28 (float4s live in scratch), WRITE 117MB
// (~9.8M staging visits x ~48B round-trips), VALUBusy 21% (scratch
// latency), 2x slowdown; R20 stores e0/e1/e2 unconditionally and never
// shows it.
//
// R26: identical to R25 except the singles select is component-wise:
//     fx = a0 ? e0.x : (a1 ? e1.x : e2.x);  (x,y,z; w=0)
// Each scalar ternary -> 2 v_cndmask_b32; all values stay in VGPRs.
// Everything else byte-identical to R25 (R20 structure + singles/triples
// sort, __expf e-domain, live/alive gating, chunking, 2x unroll).
// LDS: sBuf 1164*16B + sAcc 1KB ~= 19.7KB -> 8 blocks/CU.
//
// Prediction: WRITE_SIZE 117MB -> ~2MB, VGPR 28 -> 40+, silhouette
// 78 -> ~28-32us, dur_us -> ~72-76. If WRITE_SIZE stays high, theory
// wrong -> revert to pure R20.
//
// Error budget vs 2e-2 tolerance (absmax floor 0.00390625 = one bf16 ulp
// since R5): cull skip <= 1538*e^-12 = 9.4e-3 worst-case; inactive-edge
// approx <= 2*e^-13/face * ~150 singles ~ 7e-4; branchless factor
// ~1e-7/face; saturation cut 2.3e-6; product rounding ~1e-4.

#define IMG_S 320
#define N_FACES 1538
#define N_VERTS 778
#define N_BATCH 4
#define FP 1600            // padded face stride in ws
#define TILE 8
#define CHUNK_F 384        // faces per chunk (4 chunks: 384,384,384,386)
#define N_CHUNKS 4
#define MAXB 388           // per-chunk face capacity (>= max chunk 386)
#define NWAVE 4
#define INV_SIGMA 100.0f
#define T_CUT 12.0f
#define T_ACT 13.0f        // per-edge activity threshold (nats)
#define ACC_CUT_P 2.2603294e-6f    // e^-13, product-domain saturation
#define LOG2_1EM6 -19.9315686f     // log2(1e-6)

__global__ __launch_bounds__(256)
void prep_faces(const float* __restrict__ verts,
                const int* __restrict__ faces,
                float4* __restrict__ gE0,
                float4* __restrict__ gE1,
                float4* __restrict__ gE2)
{
    const int f = blockIdx.x * 256 + threadIdx.x;
    const int b = blockIdx.z;
    if (f >= N_FACES) return;

    const float* vb = verts + (size_t)b * N_VERTS * 3;
    const int i0 = faces[f * 3 + 0];
    const int i1 = faces[f * 3 + 1];
    const int i2 = faces[f * 3 + 2];
    const float x0 = vb[i0 * 3 + 0], y0 = -vb[i0 * 3 + 1];
    const float x1 = vb[i1 * 3 + 0], y1 = -vb[i1 * 3 + 1];
    const float x2 = vb[i2 * 3 + 0], y2 = -vb[i2 * 3 + 1];

    // VERIFIED-EXACT (R4): fma-contracted area2 — do not change.
    const float dx1 = x1 - x0, dy1 = y1 - y0;
    const float dx2 = x2 - x0, dy2 = y2 - y0;
    const float area2 = __builtin_fmaf(dx1, dy2, -__fmul_rn(dy1, dx2));
    const float sgn = (area2 > 0.0f) ? 1.0f : ((area2 < 0.0f) ? -1.0f : 0.0f);

    const size_t o = (size_t)b * FP + f;
    {   // edge v0 -> v1
        const float ex = x1 - x0, ey = y1 - y0;
        const float s = sgn * INV_SIGMA / (sqrtf(ex * ex + ey * ey) + 1e-8f);
        gE0[o] = make_float4(-s * ey, s * ex, s * (ey * x0 - ex * y0), 0.0f);
    }
    {   // edge v1 -> v2
        const float ex = x2 - x1, ey = y2 - y1;
        const float s = sgn * INV_SIGMA / (sqrtf(ex * ex + ey * ey) + 1e-8f);
        gE1[o] = make_float4(-s * ey, s * ex, s * (ey * x1 - ex * y1), 0.0f);
    }
    {   // edge v2 -> v0
        const float ex = x0 - x2, ey = y0 - y2;
        const float s = sgn * INV_SIGMA / (sqrtf(ex * ex + ey * ey) + 1e-8f);
        gE2[o] = make_float4(-s * ey, s * ex, s * (ey * x2 - ex * y2), 0.0f);
    }
}

__global__ __launch_bounds__(256)
void silhouette_ws(const float4* __restrict__ gE0,
                   const float4* __restrict__ gE1,
                   const float4* __restrict__ gE2,
                   float* __restrict__ out)
{
    __shared__ float4 sBuf[3 * MAXB];   // singles bottom-up, triples top-down
    __shared__ float sAcc[256];
    __shared__ int sCount1;
    __shared__ int sCount3;
    __shared__ int sAlive;
    __shared__ int sCover;

    const int t    = threadIdx.x;
    const int wave = t >> 6;
    const int lane = t & 63;
    const int p    = t & 63;          // pixel id within 8x8 tile
    const int plx  = p & 7;
    const int ply  = p >> 3;
    const int b    = blockIdx.z;
    const int gx   = blockIdx.x * TILE + plx;
    const int gy   = blockIdx.y * TILE + ply;

    const float w  = 2.0f / IMG_S;
    const float px = (gx + 0.5f) * w - 1.0f;
    const float py = (gy + 0.5f) * w - 1.0f;
    const float cx = (blockIdx.x * TILE + 4) * w - 1.0f;
    const float cy = (blockIdx.y * TILE + 4) * w - 1.0f;
    const float rr = 3.5f * w;

    const float4* gb0 = gE0 + (size_t)b * FP;   // per-batch base
    const float4* gb1 = gE1 + (size_t)b * FP;
    const float4* gb2 = gE2 + (size_t)b * FP;

    float acc = 1.0f;   // product of (1-prob) over this wave's face subset
                        // (wave 0 also carries the cover factors)

    for (int c = 0; c < N_CHUNKS; ++c) {
        const int base = c * CHUNK_F;
        const int end  = (c == N_CHUNKS - 1) ? N_FACES : base + CHUNK_F;

        sAcc[t] = acc;
        if (t == 0) { sCount1 = 0; sCount3 = 0; sAlive = 0; sCover = 0; }
        __syncthreads();   // B1: resets + partials visible

        const float tot = sAcc[p] * sAcc[p + 64] * sAcc[p + 128] * sAcc[p + 192];
        const bool alive = (tot > ACC_CUT_P);
        if (alive) sAlive = 1;               // benign same-value race
        __syncthreads();   // B2: vote final — break BEFORE staging
                           // (also fences prev chunk's sBuf reads from
                           //  this chunk's sBuf writes)

        if (sAlive == 0) break;   // uniform: every pixel saturated

        // ---- staging: classify, split into singles/triples, compact ----
        for (int fb = base; fb < end; fb += 256) {
            const int fc = fb + t;
            const bool vald = (fc < end);
            const int fcc = vald ? fc : (end - 1);
            const float4 e0 = gb0[fcc];      // coalesced vector loads
            const float4 e1 = gb1[fcc];
            const float4 e2 = gb2[fcc];
            const float c0 = fmaf(e0.x, cx, fmaf(e0.y, cy, e0.z));
            const float c1 = fmaf(e1.x, cx, fmaf(e1.y, cy, e1.z));
            const float c2 = fmaf(e2.x, cx, fmaf(e2.y, cy, e2.z));
            const float r0 = rr * (fabsf(e0.x) + fabsf(e0.y));
            const float r1 = rr * (fabsf(e1.x) + fabsf(e1.y));
            const float r2 = rr * (fabsf(e2.x) + fabsf(e2.y));
            const float m_hi = fminf(c0 + r0, fminf(c1 + r1, c2 + r2));
            const float m_lo = fminf(c0 - r0, fminf(c1 - r1, c2 - r2));
            const bool isCov  = vald && (m_lo > T_CUT);
            const bool isBand = vald && !isCov && (m_hi > -T_CUT);

            const bool a0 = (c0 - r0) <= T_ACT;   // edge active over tile
            const bool a1 = (c1 - r1) <= T_ACT;
            const bool a2 = (c2 - r2) <= T_ACT;
            const int cnt = (int)a0 + (int)a1 + (int)a2;
            const bool isS = isBand && (cnt <= 1);
            const bool isT = isBand && (cnt >= 2);

            {   // singles compaction (bottom-up)
                const unsigned long long ms = __ballot(isS);
                int wb = 0;
                if (lane == 0) {
                    const int nw = __popcll(ms);
                    if (nw) wb = atomicAdd(&sCount1, nw);
                }
                wb = __shfl(wb, 0);
                if (isS) {
                    const int pos = wb + __popcll(ms & ((1ull << lane) - 1ull));
                    // COMPONENT-WISE select (rule-#20 fix): each scalar
                    // ternary lowers to v_cndmask — no aggregate select,
                    // no scratch demotion.
                    const float fx = a0 ? e0.x : (a1 ? e1.x : e2.x);
                    const float fy = a0 ? e0.y : (a1 ? e1.y : e2.y);
                    const float fz = a0 ? e0.z : (a1 ? e1.z : e2.z);
                    sBuf[pos] = make_float4(fx, fy, fz, 0.0f);
                }
            }
            {   // triples compaction (top-down)
                const unsigned long long mt = __ballot(isT);
                int wb = 0;
                if (lane == 0) {
                    const int nw = __popcll(mt);
                    if (nw) wb = atomicAdd(&sCount3, nw);
                }
                wb = __shfl(wb, 0);
                if (isT) {
                    const int pos = wb + __popcll(mt & ((1ull << lane) - 1ull));
                    const int bix = 3 * MAXB - 3 * (pos + 1);
                    sBuf[bix + 0] = e0;      // unconditional stores — safe
                    sBuf[bix + 1] = e1;
                    sBuf[bix + 2] = e2;
                }
            }
            const unsigned long long mc = __ballot(isCov);
            if (lane == 0) {
                const int ncv = __popcll(mc);
                if (ncv) atomicAdd(&sCover, ncv);
            }
        }
        __syncthreads();   // B3: compaction + cover count final

        const float coverF = exp2f((float)sCover * LOG2_1EM6);
        bool live = alive && (acc * coverF > ACC_CUT_P);
        if (wave == 0) acc *= coverF;

        // ---- phase 1: singles — 2 trans/face, R20 gating ----
        const int n1 = sCount1;
        int j = wave;
        while (j < n1) {
            if (__ballot(live) == 0ull) break;   // whole wave saturated
            const int j1 = j + NWAVE;
            const int j1c = (j1 < n1) ? j1 : j;
            const float4 A = sBuf[j];        // both loads issued up-front
            const float4 B = sBuf[j1c];
            {
                const float x = fmaf(A.x, px, fmaf(A.y, py, A.z));
                if (live) {
                    acc *= fmaxf(__builtin_amdgcn_rcpf(1.0f + __expf(x)),
                                 1e-6f);
                    live = (acc > ACC_CUT_P);
                }
            }
            if (j1 < n1) {
                const float x = fmaf(B.x, px, fmaf(B.y, py, B.z));
                if (live) {
                    acc *= fmaxf(__builtin_amdgcn_rcpf(1.0f + __expf(x)),
                                 1e-6f);
                    live = (acc > ACC_CUT_P);
                }
            }
            j += 2 * NWAVE;
        }

        // ---- phase 2: triples — R20's exact branchless body ----
        const int n3 = sCount3;
        j = wave;
        while (j < n3) {
            if (__ballot(live) == 0ull) break;   // whole wave saturated
            const int j1 = j + NWAVE;
            const int j1c = (j1 < n3) ? j1 : j;
            const int bx0 = 3 * MAXB - 3 * (j + 1);
            const int bx1 = 3 * MAXB - 3 * (j1c + 1);
            // all 6 loads issued before any compute
            const float4 A0 = sBuf[bx0], A1 = sBuf[bx0 + 1], A2 = sBuf[bx0 + 2];
            const float4 B0 = sBuf[bx1], B1 = sBuf[bx1 + 1], B2 = sBuf[bx1 + 2];
            {   // iteration 0
                const float xa = fmaf(A0.x, px, fmaf(A0.y, py, A0.z));
                const float xb = fmaf(A1.x, px, fmaf(A1.y, py, A1.z));
                const float xc = fmaf(A2.x, px, fmaf(A2.y, py, A2.z));
                const float m = fminf(xa, fminf(xb, xc));
                if (live && m > -T_CUT) {
                    const float da = 1.0f + __expf(-xa);
                    const float db = 1.0f + __expf(-xb);
                    const float dc = 1.0f + __expf(-xc);
                    const float f = fmaxf(
                        1.0f - __builtin_amdgcn_rcpf(da * db * dc), 1e-6f);
                    acc *= f;
                    live = (acc > ACC_CUT_P);
                }
            }
            if (j1 < n3) {   // iteration 1
                const float xa = fmaf(B0.x, px, fmaf(B0.y, py, B0.z));
                const float xb = fmaf(B1.x, px, fmaf(B1.y, py, B1.z));
                const float xc = fmaf(B2.x, px, fmaf(B2.y, py, B2.z));
                const float m = fminf(xa, fminf(xb, xc));
                if (live && m > -T_CUT) {
                    const float da = 1.0f + __expf(-xa);
                    const float db = 1.0f + __expf(-xb);
                    const float dc = 1.0f + __expf(-xc);
                    const float f = fmaxf(
                        1.0f - __builtin_amdgcn_rcpf(da * db * dc), 1e-6f);
                    acc *= f;
                    live = (acc > ACC_CUT_P);
                }
            }
            j += 2 * NWAVE;
        }
        // no B4: next chunk's sBuf writes happen after its B2, which every
        // wave passes only after finishing both phases.
    }

    // final reduction + output (loop exits are block-uniform)
    sAcc[t] = acc;
    __syncthreads();
    if (t < 64) {
        const float tot = sAcc[p] * sAcc[p + 64] * sAcc[p + 128] * sAcc[p + 192];
        out[(size_t)b * (IMG_S * IMG_S) + (size_t)gy * IMG_S + gx] = 1.0f - tot;
    }
}

extern "C" void kernel_launch(void* const* d_in, const int* in_sizes, int n_in,
                              void* d_out, int out_size, void* d_ws, size_t ws_size,
                              hipStream_t stream) {
    const float* verts = (const float*)d_in[0];
    const int* faces = (const int*)d_in[1];
    float* out = (float*)d_out;

    // ws layout: 3 arrays of float4[N_BATCH * FP]  (3 * 4*1600*16B = 307 KB)
    float4* gE0 = (float4*)d_ws;
    float4* gE1 = gE0 + (size_t)N_BATCH * FP;
    float4* gE2 = gE1 + (size_t)N_BATCH * FP;

    dim3 pgrid((N_FACES + 255) / 256, 1, N_BATCH);
    prep_faces<<<pgrid, 256, 0, stream>>>(verts, faces, gE0, gE1, gE2);

    dim3 grid(IMG_S / TILE, IMG_S / TILE, N_BATCH);
    silhouette_ws<<<grid, 256, 0, stream>>>(gE0, gE1, gE2, out);
}